// Round 2
// baseline (617.960 us; speedup 1.0000x reference)
//
#include <hip/hip_runtime.h>
#include <stdint.h>

typedef _Float16 f16;
typedef _Float16 f16x8 __attribute__((ext_vector_type(8)));
typedef _Float16 f16x4 __attribute__((ext_vector_type(4)));
typedef float f32x4 __attribute__((ext_vector_type(4)));
typedef int int4v __attribute__((ext_vector_type(4)));
typedef float float4v __attribute__((ext_vector_type(4)));

#define S_LEN 2048
#define D_DIM 64
#define QBLK 128
#define KBLK 64
#define NTHREADS 512
#define KSTEPS (S_LEN / KBLK)   // 32

__device__ __forceinline__ f16x8 cvt8(float4v a, float4v b) {
    f16x8 f;
    f[0]=(f16)a[0]; f[1]=(f16)a[1]; f[2]=(f16)a[2]; f[3]=(f16)a[3];
    f[4]=(f16)b[0]; f[5]=(f16)b[1]; f[6]=(f16)b[2]; f[7]=(f16)b[3];
    return f;
}
__device__ __forceinline__ uint32_t f16b(float x) {
    union { f16 h; uint16_t u; } c; c.h = (f16)x; return c.u;
}

__global__ __launch_bounds__(NTHREADS, 4)
void sdpa_kernel(const float* __restrict__ Qg, const float* __restrict__ Kg,
                 const float* __restrict__ Vg, const int* __restrict__ Mg,
                 float* __restrict__ ProbOut, float* __restrict__ AttnOut)
{
    // LDS: 16 (K dbuf) + 16 (Vt dbuf) + 16 (P) + 32 (mask bits) = 80 KB -> 2 blocks/CU
    __shared__ f16 Klds[2][KBLK * D_DIM];       // [k][d] rows XOR-swizzled
    __shared__ f16 Vtlds[2][D_DIM * KBLK];      // [d][k] rows XOR-swizzled
    __shared__ f16 Plds[8][16 * KBLK];          // per-wave P tile [q16][k64]
    __shared__ uint16_t Mw[KSTEPS][NTHREADS];   // mask bits, 16 per thread per kstep

    const int tid  = threadIdx.x;
    const int wq   = tid >> 6;
    const int lane = tid & 63;
    const int g    = lane >> 4;
    const int lr   = lane & 15;

    // XCD-aware swizzle: each XCD gets 128 consecutive logical blocks (~4 heads resident)
    const int wid = ((blockIdx.x & 7) << 7) + (blockIdx.x >> 3);
    const int bh  = wid >> 4;
    const int qb  = wid & 15;

    const size_t qkv_base = (size_t)bh * S_LEN * D_DIM;
    const size_t mat_base = (size_t)bh * S_LEN * S_LEN;
    const int qw0 = qb * QBLK + wq * 16;

    // ---- Q fragment: lane holds Q[qw0+lr][d = 8g+i+32h] (B-operand layout) ----
    f16x8 qfrag[2];
    {
        const float* qp = Qg + qkv_base + (size_t)(qw0 + lr) * D_DIM + g * 8;
        #pragma unroll
        for (int h = 0; h < 2; ++h)
            qfrag[h] = cvt8(*(const float4v*)(qp + 32 * h),
                            *(const float4v*)(qp + 32 * h + 4));
    }

    // staging assignments
    const int srow = tid >> 3, scol = (tid & 7) * 8;
    const int sidx = (srow * D_DIM + scol) ^ ((srow & 7) << 3);
    const int vrp  = tid >> 4, vdb = (tid & 15) * 4;

    const float* kbase = Kg + qkv_base;
    const float* vbase = Vg + qkv_base;
    const int*   mbase = Mg + mat_base + (size_t)(qw0 + lr) * S_LEN + 4 * g;

    // ================= sweep 1: l = sum(exp(s)), record mask bits =================
    float lacc[4] = {0.f, 0.f, 0.f, 0.f};

    float4v ka, kb;
    {   // prologue: K(0) -> LDS[0], mask(0) -> regs
        const float* kp = kbase + (size_t)srow * D_DIM + scol;
        ka = *(const float4v*)kp; kb = *(const float4v*)(kp + 4);
    }
    int4v mreg[4];
    #pragma unroll
    for (int ct = 0; ct < 4; ++ct)
        mreg[ct] = __builtin_nontemporal_load((const int4v*)(mbase + 16 * ct));
    *(f16x8*)&Klds[0][sidx] = cvt8(ka, kb);

    for (int t = 0; t < KSTEPS; ++t) {
        const int cur = t & 1;
        __syncthreads();
        if (t + 1 < KSTEPS) {   // issue next K tile loads early
            const float* kp = kbase + (size_t)((t + 1) * KBLK + srow) * D_DIM + scol;
            ka = *(const float4v*)kp; kb = *(const float4v*)(kp + 4);
        }
        // swapped QK^T: c[ct][r] = S[q=qw0+lr][k = t*64 + 16ct + 4g + r]
        f32x4 c[4];
        #pragma unroll
        for (int ct = 0; ct < 4; ++ct) {
            c[ct] = (f32x4){0.f, 0.f, 0.f, 0.f};
            #pragma unroll
            for (int h = 0; h < 2; ++h) {
                int rowl = 16 * ct + lr;
                int idx = (rowl * D_DIM + 8 * g + 32 * h) ^ ((rowl & 7) << 3);
                f16x8 kf = *(const f16x8*)(&Klds[cur][idx]);
                c[ct] = __builtin_amdgcn_mfma_f32_16x16x32_f16(kf, qfrag[h], c[ct], 0, 0, 0);
            }
        }
        uint32_t bits = 0;
        #pragma unroll
        for (int ct = 0; ct < 4; ++ct) {
            #pragma unroll
            for (int r = 0; r < 4; ++r) {
                float s = c[ct][r] * 0.125f;
                bool mk = (mreg[ct][r] != 0);
                bits |= (mk ? 1u : 0u) << (4 * ct + r);
                float p = mk ? 0.f : __expf(s);   // fixed-C softmax: |s| <= 8
                lacc[r] += p;
            }
        }
        Mw[t][tid] = (uint16_t)bits;
        if (t + 1 < KSTEPS) {   // prefetch next mask tile
            #pragma unroll
            for (int ct = 0; ct < 4; ++ct)
                mreg[ct] = __builtin_nontemporal_load(
                    (const int4v*)(mbase + (t + 1) * KBLK + 16 * ct));
        }
        if (t + 1 < KSTEPS)     // write next K tile (loads have landed under compute)
            *(f16x8*)&Klds[cur ^ 1][sidx] = cvt8(ka, kb);
    }

    float lsum = (lacc[0] + lacc[1]) + (lacc[2] + lacc[3]);
    lsum += __shfl_xor(lsum, 16, 64);
    lsum += __shfl_xor(lsum, 32, 64);        // row sum for q = qw0+lr in all 4 g-lanes
    const float inv_l = 1.f / lsum;

    // ================= sweep 2: recompute s, write attn, PV =================
    f32x4 acc[4];
    #pragma unroll
    for (int dt = 0; dt < 4; ++dt) acc[dt] = (f32x4){0.f, 0.f, 0.f, 0.f};

    float4v va, vb;
    {   // prologue: K(0), V(0) -> LDS[0]   (buf0 unused by waves still in sweep-1 tail)
        const float* kp = kbase + (size_t)srow * D_DIM + scol;
        ka = *(const float4v*)kp; kb = *(const float4v*)(kp + 4);
        const float* vp = vbase + (size_t)(2 * vrp) * D_DIM + vdb;
        va = *(const float4v*)vp; vb = *(const float4v*)(vp + D_DIM);
    }
    *(f16x8*)&Klds[0][sidx] = cvt8(ka, kb);
    #pragma unroll
    for (int j = 0; j < 4; ++j) {
        int d = vdb + j;
        uint32_t pk = f16b(va[j]) | (f16b(vb[j]) << 16);
        *(uint32_t*)&Vtlds[0][(d * KBLK + 2 * vrp) ^ ((d & 7) << 3)] = pk;
    }

    for (int t = 0; t < KSTEPS; ++t) {
        const int cur = t & 1;
        __syncthreads();
        if (t + 1 < KSTEPS) {
            const float* kp = kbase + (size_t)((t + 1) * KBLK + srow) * D_DIM + scol;
            ka = *(const float4v*)kp; kb = *(const float4v*)(kp + 4);
            const float* vp = vbase + (size_t)((t + 1) * KBLK + 2 * vrp) * D_DIM + vdb;
            va = *(const float4v*)vp; vb = *(const float4v*)(vp + D_DIM);
        }
        f32x4 c[4];
        #pragma unroll
        for (int ct = 0; ct < 4; ++ct) {
            c[ct] = (f32x4){0.f, 0.f, 0.f, 0.f};
            #pragma unroll
            for (int h = 0; h < 2; ++h) {
                int rowl = 16 * ct + lr;
                int idx = (rowl * D_DIM + 8 * g + 32 * h) ^ ((rowl & 7) << 3);
                f16x8 kf = *(const f16x8*)(&Klds[cur][idx]);
                c[ct] = __builtin_amdgcn_mfma_f32_16x16x32_f16(kf, qfrag[h], c[ct], 0, 0, 0);
            }
        }
        const uint32_t bits = Mw[t][tid];
        #pragma unroll
        for (int ct = 0; ct < 4; ++ct) {
            float4v av; f16x4 pv;
            #pragma unroll
            for (int r = 0; r < 4; ++r) {
                float s = c[ct][r] * 0.125f;
                float p = ((bits >> (4 * ct + r)) & 1) ? 0.f : __expf(s);
                float pn = p * inv_l;
                av[r] = pn; pv[r] = (f16)pn;
            }
            __builtin_nontemporal_store(av,
                (float4v*)(AttnOut + mat_base + (size_t)(qw0 + lr) * S_LEN
                           + t * KBLK + 16 * ct + 4 * g));
            *(f16x4*)&Plds[wq][(lr * KBLK + 16 * ct + 4 * g) ^ ((lr & 7) << 3)] = pv;
        }
        // PV: acc[dt] += P(16x64) * V(64x64), P normalized -> acc is final prob
        #pragma unroll
        for (int h = 0; h < 2; ++h) {
            f16x8 pa = *(const f16x8*)&Plds[wq][(lr * KBLK + 8 * g + 32 * h) ^ ((lr & 7) << 3)];
            #pragma unroll
            for (int dt = 0; dt < 4; ++dt) {
                int rowd = 16 * dt + lr;
                f16x8 vf = *(const f16x8*)&Vtlds[cur][(rowd * KBLK + 8 * g + 32 * h) ^ ((rowd & 7) << 3)];
                acc[dt] = __builtin_amdgcn_mfma_f32_16x16x32_f16(pa, vf, acc[dt], 0, 0, 0);
            }
        }
        if (t + 1 < KSTEPS) {
            *(f16x8*)&Klds[cur ^ 1][sidx] = cvt8(ka, kb);
            #pragma unroll
            for (int j = 0; j < 4; ++j) {
                int d = vdb + j;
                uint32_t pk = f16b(va[j]) | (f16b(vb[j]) << 16);
                *(uint32_t*)&Vtlds[cur ^ 1][(d * KBLK + 2 * vrp) ^ ((d & 7) << 3)] = pk;
            }
        }
    }

    // epilogue: prob (already normalized)
    #pragma unroll
    for (int dt = 0; dt < 4; ++dt) {
        #pragma unroll
        for (int r = 0; r < 4; ++r) {
            int qrow = qw0 + 4 * g + r;
            ProbOut[qkv_base + (size_t)qrow * D_DIM + 16 * dt + lr] = acc[dt][r];
        }
    }
}

extern "C" void kernel_launch(void* const* d_in, const int* in_sizes, int n_in,
                              void* d_out, int out_size, void* d_ws, size_t ws_size,
                              hipStream_t stream)
{
    const float* Q = (const float*)d_in[0];
    const float* K = (const float*)d_in[1];
    const float* V = (const float*)d_in[2];
    const int*   M = (const int*)d_in[3];

    float* prob = (float*)d_out;                          // [4,16,2048,64]
    float* attn = prob + (size_t)4 * 16 * 2048 * 64;      // [4,16,2048,2048]

    dim3 grid(64 * (S_LEN / QBLK));   // 1024
    dim3 block(NTHREADS);
    sdpa_kernel<<<grid, block, 0, stream>>>(Q, K, V, M, prob, attn);
}